// Round 21
// baseline (202.787 us; speedup 1.0000x reference)
//
#include <hip/hip_runtime.h>
#include <hip/hip_bf16.h>

constexpr int kN = 8192;
constexpr int kD = 128;
constexpr int BM = 32;      // rows per block in gemm kernel (2 MFMA row-tiles)
constexpr int BK = 64;      // j-chunk (2 fragment windows)
constexpr int JSPLIT = 8;   // j-range strips for gemm_k (grid at 2048 blocks)
constexpr int KJS = 8;      // j-range strips for kwrite_k (grid at 4096 blocks)
constexpr int LDB = 72;     // A-tile LDS row stride: 144B, 16B-aligned (r19-proven)
constexpr int TB = 64;      // rowsum tile
constexpr int NB = kN / TB; // 128

typedef __bf16 v8bf __attribute__((ext_vector_type(8)));
typedef float  v4f  __attribute__((ext_vector_type(4)));

// K_raw with 3 transcendentals (round-8 proven).
__device__ __forceinline__ float kraw_f(float4 ci, float sqi, float4 cj, float sqj) {
    float d2 = sqi + sqj - 2.0f * (ci.x * cj.x + ci.y * cj.y + ci.z * cj.z);
    d2 = fmaxf(d2, 1e-12f);
    float Dd = __builtin_amdgcn_sqrtf(d2);
    float a = 0.5f * (ci.w + cj.w);
    float t = a * (-0.5f * __builtin_amdgcn_logf(d2));                // -a*log2(D)
    t = fminf(fmaxf(t, -26.575424759098897f), 9.965784284662087f);   // log2(1e-8), log2(1000)
    float K = __builtin_amdgcn_exp2f(fmaf(Dd, -0.12022458674074695f, t));
    return fminf(K, 1000.0f);  // K >= 0 always
}

// --- kernel 1: pack coords+alpha into float4; zero rsum (r18 proven) -------
__global__ void pack_k(const float* __restrict__ coords, const float* __restrict__ alpha,
                       float4* __restrict__ c4, float* __restrict__ rsum) {
    int j = blockIdx.x * 256 + threadIdx.x;
    if (j < kN) {
        c4[j] = make_float4(coords[3 * j], coords[3 * j + 1], coords[3 * j + 2], alpha[j]);
        rsum[j] = 0.0f;   // consumed by rowsum_sym_k (later in stream order)
    }
}

// --- kernel 2: fragment-native B prep (r14/r20 proven); zeroes outp --------
__global__ __launch_bounds__(256) void fragprep_k(const float* __restrict__ latent,
                                                  __bf16* __restrict__ latTf,
                                                  float* __restrict__ outp) {
    __shared__ float ltile[32][132];   // 32 j-rows x 128 dims (pad 4)
    const int jw = blockIdx.x;
    const int t = threadIdx.x;

    #pragma unroll
    for (int it = 0; it < 4; ++it) {
        int idx = it * 256 + t;            // 0..1023
        int row = idx >> 5;                // 0..31
        int col = (idx & 31) * 4;          // 0..124
        float4 v = *reinterpret_cast<const float4*>(
            latent + (size_t)(jw * 32 + row) * kD + col);
        *reinterpret_cast<float4*>(&ltile[row][col]) = v;
    }

    // zero outp: 256 blocks x 256 threads x 16 floats = kN*kD, bijective.
    {
        size_t base = ((size_t)jw * 256 + t) * 16;
        v4f z = {0.f, 0.f, 0.f, 0.f};
        #pragma unroll
        for (int e = 0; e < 4; ++e)
            *reinterpret_cast<v4f*>(outp + base + e * 4) = z;
    }
    __syncthreads();

    #pragma unroll
    for (int ss = 0; ss < 2; ++ss) {
        int s = ss * 256 + t;              // 0..511 fragment slots
        int d = s >> 6, l = s & 63;
        int jr = (l >> 4) * 8, dim = d * 16 + (l & 15);
        unsigned w[4];
        #pragma unroll
        for (int e2 = 0; e2 < 4; ++e2) {
            __bf16 lo = (__bf16)ltile[jr + 2 * e2][dim];
            __bf16 hi = (__bf16)ltile[jr + 2 * e2 + 1][dim];
            w[e2] = ((unsigned)*(unsigned short*)&hi << 16) | *(unsigned short*)&lo;
        }
        uint4 out = {w[0], w[1], w[2], w[3]};
        *reinterpret_cast<uint4*>((char*)latTf + (((size_t)jw * 8 + d) * 64 + l) * 16) = out;
    }
}

// --- kernel 3: SYMMETRIC row sums (round-11 proven) ------------------------
__global__ __launch_bounds__(256) void rowsum_sym_k(const float4* __restrict__ c4,
                                                    float* __restrict__ rsum) {
    __shared__ float4 rc4[TB];
    __shared__ float  rsq[TB];
    __shared__ float  rowbuf[TB][TB + 1];   // 16.25 KB

    // decode triangular pair (bi <= bj) from linear block index
    int L = blockIdx.x;
    int bi = (int)((2 * NB + 1 - sqrtf((float)((2 * NB + 1) * (2 * NB + 1) - 8 * L))) * 0.5f);
    #pragma unroll
    for (int f = 0; f < 2; ++f) {
        int s0 = bi * NB - bi * (bi - 1) / 2;
        int s1 = (bi + 1) * NB - (bi + 1) * bi / 2;
        if (L >= s1) ++bi;
        else if (L < s0) --bi;
    }
    int sbi = bi * NB - bi * (bi - 1) / 2;
    int bj = bi + (L - sbi);
    bool diag = (bi == bj);

    const int t = threadIdx.x;
    const int l = t & 63;
    const int w = t >> 6;

    if (t < TB) {
        float4 ci = c4[bi * TB + t];
        rc4[t] = ci;
        rsq[t] = ci.x * ci.x + ci.y * ci.y + ci.z * ci.z;
    }
    __syncthreads();

    float4 cj = c4[bj * TB + l];
    float sqj = cj.x * cj.x + cj.y * cj.y + cj.z * cj.z;

    float colacc = 0.f;
    #pragma unroll
    for (int rr = 0; rr < 16; ++rr) {
        int r = w * 16 + rr;
        float k = kraw_f(rc4[r], rsq[r], cj, sqj);
        if (diag && r == l) k = 0.f;
        colacc += k;
        rowbuf[r][l] = k;
    }
    __syncthreads();

    // row sums: thread t -> row r = t>>2, quarter q = t&3 (adjacent lanes)
    {
        int r = t >> 2, q = t & 3;
        float p = 0.f;
        #pragma unroll
        for (int m = 0; m < 16; ++m) p += rowbuf[r][q * 16 + m];
        p += __shfl_xor(p, 1, 64);
        p += __shfl_xor(p, 2, 64);
        if (q == 0) atomicAdd(&rsum[bi * TB + r], p);
    }
    if (!diag) atomicAdd(&rsum[bj * TB + l], colacc);
}

// --- kernel 4: PURE STREAMING K writer — zero LDS, zero barriers -----------
// r4-proven mapping: block = 4 independent waves, 16 rows; wave w owns a
// (kN/KJS/4)-col substrip; thread = row lane&15, 8 consecutive cols. kraw ->
// normalize -> two v4f stores. The kraw issue cost (~22us chip-wide) hides
// under the 268MB write stream; no phase coupling.
__global__ __launch_bounds__(256) void kwrite_k(
    const float4* __restrict__ c4, const float* __restrict__ rsum,
    float* __restrict__ Kout) {

    const int t = threadIdx.x;
    const int lane = t & 63;
    const int wave = t >> 6;
    const int i0 = blockIdx.x * 16;
    const int gi = i0 + (lane & 15);
    const int koff = (lane >> 4) * 8;

    const float4 ci = c4[gi];
    const float sqi = ci.x * ci.x + ci.y * ci.y + ci.z * ci.z;
    const float inv_i = 1.0f / (rsum[gi] + 1e-8f);

    const int jbase = blockIdx.y * (kN / KJS) + wave * (kN / KJS / 4);
    constexpr int NIT = kN / KJS / 4 / 32;   // windows of 32 cols

    for (int cb = 0; cb < NIT; ++cb) {
        const int jc = jbase + cb * 32 + koff;

        float kn[8];
        #pragma unroll
        for (int e = 0; e < 8; ++e) {
            float4 cj = c4[jc + e];
            float sqj = cj.x * cj.x + cj.y * cj.y + cj.z * cj.z;
            float k = (gi == jc + e) ? 0.0f : kraw_f(ci, sqi, cj, sqj);
            kn[e] = k * inv_i;
        }

        float* kp = Kout + (size_t)gi * kN + jc;
        v4f s0 = {kn[0], kn[1], kn[2], kn[3]};
        v4f s1 = {kn[4], kn[5], kn[6], kn[7]};
        *reinterpret_cast<v4f*>(kp)     = s0;
        *reinterpret_cast<v4f*>(kp + 4) = s1;
    }
}

// --- kernel 5: GEMM out = K @ latent — r20 structure, A loaded not computed -
// Identical to the r19/r20-proven main_k except the A-production phase is a
// coalesced f32 load of the K tile (2 rows x 256B per instruction in the
// proven producer mapping) -> bf16 -> Alds. Values bit-identical to r20's.
// K re-read is mostly L3-resident (written just before, 268MB vs 256MB L3).
__global__ __launch_bounds__(256, 2) void gemm_k(
    const float* __restrict__ Kin, const __bf16* __restrict__ latTf,
    float* __restrict__ outp) {

    __shared__ __bf16 Alds[BM][LDB];    // 4.6 KB, K tile as bf16

    const int t = threadIdx.x;
    const int i0 = blockIdx.x * BM;
    const int jstrip = blockIdx.y * (kN / JSPLIT);

    const int lane = t & 63;
    const int wave = t >> 6;

    // A-tile load mapping (proven producer mapping): col pair {2c2, 2c2+1},
    // rows rb..rb+3
    const int c2 = t & 31;
    const int rb = (t >> 5) * 4;

    // MFMA fragment addressing (r9/r10-proven A; r14/r20-proven B)
    const int arow = lane & 15;
    const int koff = (lane >> 4) * 8;          // elements
    const char* bfb = (const char*)latTf + (size_t)lane * 16;

    v4f acc[2][2];
    #pragma unroll
    for (int rt = 0; rt < 2; ++rt)
        #pragma unroll
        for (int dt = 0; dt < 2; ++dt) acc[rt][dt] = (v4f){0.f, 0.f, 0.f, 0.f};

    for (int cb = 0; cb < kN / JSPLIT / BK; ++cb) {
        const int j0 = jstrip + cb * BK;
        const int gjA = j0 + 2 * c2;

        // load K tile (32 x 64 f32): coalesced 256B per 32-lane row-group
        #pragma unroll
        for (int rr = 0; rr < 4; ++rr) {
            int r = rb + rr, gi = i0 + r;
            float2 kn = *reinterpret_cast<const float2*>(Kin + (size_t)gi * kN + gjA);
            __bf16 hA = (__bf16)kn.x, hB = (__bf16)kn.y;
            unsigned pk = ((unsigned)*(unsigned short*)&hB << 16) | *(unsigned short*)&hA;
            *reinterpret_cast<unsigned*>(&Alds[r][2 * c2]) = pk;
        }
        __syncthreads();

        // MFMA: A row-tiles {0,1} x B dim-tiles {0,1}; B direct from latTf
        #pragma unroll
        for (int kk = 0; kk < 2; ++kk) {
            const size_t jw = (size_t)(j0 >> 5) + kk;       // 32-col window index
            v8bf a0 = *reinterpret_cast<const v8bf*>(&Alds[arow][kk * 32 + koff]);
            v8bf a1 = *reinterpret_cast<const v8bf*>(&Alds[16 + arow][kk * 32 + koff]);
            v8bf b0 = *reinterpret_cast<const v8bf*>(bfb + (jw * 8 + wave * 2)     * 1024);
            v8bf b1 = *reinterpret_cast<const v8bf*>(bfb + (jw * 8 + wave * 2 + 1) * 1024);
            acc[0][0] = __builtin_amdgcn_mfma_f32_16x16x32_bf16(a0, b0, acc[0][0], 0, 0, 0);
            acc[0][1] = __builtin_amdgcn_mfma_f32_16x16x32_bf16(a0, b1, acc[0][1], 0, 0, 0);
            acc[1][0] = __builtin_amdgcn_mfma_f32_16x16x32_bf16(a1, b0, acc[1][0], 0, 0, 0);
            acc[1][1] = __builtin_amdgcn_mfma_f32_16x16x32_bf16(a1, b1, acc[1][1], 0, 0, 0);
        }
        __syncthreads();
    }

    // epilogue: D frag col = lane&15 (dim), row = (lane>>4)*4 + q  [m89 proven]
    const int row = (lane >> 4) * 4;
    const int col0 = wave * 32 + (lane & 15);
    #pragma unroll
    for (int rt = 0; rt < 2; ++rt)
        #pragma unroll
        for (int dt = 0; dt < 2; ++dt)
            #pragma unroll
            for (int q = 0; q < 4; ++q)
                atomicAdd(&outp[(size_t)(i0 + rt * 16 + row + q) * kD + col0 + dt * 16],
                          acc[rt][dt][q]);
}

extern "C" void kernel_launch(void* const* d_in, const int* in_sizes, int n_in,
                              void* d_out, int out_size, void* d_ws, size_t ws_size,
                              hipStream_t stream) {
    const float* latent = (const float*)d_in[0];
    const float* coords = (const float*)d_in[1];
    const float* alpha  = (const float*)d_in[2];

    float* outp = (float*)d_out;                    // [8192][128]
    float* Kout = (float*)d_out + (size_t)kN * kD;  // [8192][8192]

    // ws layout: byte-identical to the proven footprint.
    char* ws = (char*)d_ws;
    __bf16* latTf = (__bf16*)ws;                                  // 2 MiB
    float4* c4    = (float4*)(ws + 2u * 1024 * 1024);             // 128 KiB
    float*  rsum  = (float*)(ws + 2u * 1024 * 1024 + 128 * 1024); // 32 KiB

    pack_k<<<dim3(kN / 256), dim3(256), 0, stream>>>(coords, alpha, c4, rsum);
    fragprep_k<<<dim3(kN / 32), dim3(256), 0, stream>>>(latent, latTf, outp);
    rowsum_sym_k<<<dim3(NB * (NB + 1) / 2), dim3(256), 0, stream>>>(c4, rsum);
    kwrite_k<<<dim3(kN / 16, KJS), dim3(256), 0, stream>>>(c4, rsum, Kout);
    gemm_k<<<dim3(kN / BM, JSPLIT), dim3(256), 0, stream>>>(Kout, latTf, outp);
}

// Round 22
// 112.900 us; speedup vs baseline: 1.7962x; 1.7962x over previous
//
#include <hip/hip_runtime.h>
#include <hip/hip_bf16.h>

constexpr int kN = 8192;
constexpr int kD = 128;
constexpr int BM = 32;      // rows per block in main kernel (2 MFMA row-tiles)
constexpr int BK = 64;      // j-chunk
constexpr int JSPLIT = 8;   // j-range strips (grid at 2048 blocks)
constexpr int LDB = 72;     // A-tile LDS row stride: 144B, 16B-aligned (r19-proven)
constexpr int TB = 64;      // rowsum tile
constexpr int NB = kN / TB; // 128

typedef __bf16 v8bf __attribute__((ext_vector_type(8)));
typedef float  v4f  __attribute__((ext_vector_type(4)));

// async global->LDS, 16B per lane (r10-proven).
__device__ __forceinline__ void gload16(const void* g, void* l) {
    __builtin_amdgcn_global_load_lds(
        (const __attribute__((address_space(1))) void*)g,
        (__attribute__((address_space(3))) void*)l, 16, 0, 0);
}

// K_raw with 3 transcendentals (round-8 proven).
__device__ __forceinline__ float kraw_f(float4 ci, float sqi, float4 cj, float sqj) {
    float d2 = sqi + sqj - 2.0f * (ci.x * cj.x + ci.y * cj.y + ci.z * cj.z);
    d2 = fmaxf(d2, 1e-12f);
    float Dd = __builtin_amdgcn_sqrtf(d2);
    float a = 0.5f * (ci.w + cj.w);
    float t = a * (-0.5f * __builtin_amdgcn_logf(d2));                // -a*log2(D)
    t = fminf(fmaxf(t, -26.575424759098897f), 9.965784284662087f);   // log2(1e-8), log2(1000)
    float K = __builtin_amdgcn_exp2f(fmaf(Dd, -0.12022458674074695f, t));
    return fminf(K, 1000.0f);  // K >= 0 always
}

// --- kernel 1: transpose latent -> latT bf16; zero outp; fused pack --------
// blockIdx.y==0 blocks additionally pack coords+alpha -> c4 and zero rsum for
// their 32-point chunk (stream order guarantees completion before rowsum).
__global__ void transpose_k(const float* __restrict__ latent,
                            const float* __restrict__ coords,
                            const float* __restrict__ alpha,
                            __bf16* __restrict__ latT, float* __restrict__ outp,
                            float4* __restrict__ c4, float* __restrict__ rsum) {
    __shared__ float tile[32][33];
    int t = threadIdx.x;
    int tx = t & 31, ty = t >> 5;          // 32 x 8
    int j0 = blockIdx.x * 32, d0 = blockIdx.y * 32;

    if (blockIdx.y == 0 && t < 32) {
        int j = blockIdx.x * 32 + t;       // 256 x 32 = 8192 points
        c4[j] = make_float4(coords[3 * j], coords[3 * j + 1], coords[3 * j + 2], alpha[j]);
        rsum[j] = 0.0f;                    // consumed by rowsum_sym_k
    }

    #pragma unroll
    for (int i = 0; i < 32; i += 8)
        tile[ty + i][tx] = latent[(size_t)(j0 + ty + i) * kD + d0 + tx];

    // zero outp: grid (256,4) x 256 threads x 4 floats = kN*kD, bijective.
    {
        size_t base = (((size_t)blockIdx.x * 4 + blockIdx.y) * 256 + t) * 4;
        v4f z = {0.f, 0.f, 0.f, 0.f};
        *reinterpret_cast<v4f*>(outp + base) = z;   // consumed by main_k later
    }
    __syncthreads();
    #pragma unroll
    for (int i = 0; i < 32; i += 8)
        latT[(size_t)(d0 + ty + i) * kN + j0 + tx] = (__bf16)tile[tx][ty + i];
}

// --- kernel 2: SYMMETRIC row sums (round-11 proven) ------------------------
__global__ __launch_bounds__(256) void rowsum_sym_k(const float4* __restrict__ c4,
                                                    float* __restrict__ rsum) {
    __shared__ float4 rc4[TB];
    __shared__ float  rsq[TB];
    __shared__ float  rowbuf[TB][TB + 1];   // 16.25 KB

    // decode triangular pair (bi <= bj) from linear block index
    int L = blockIdx.x;
    int bi = (int)((2 * NB + 1 - sqrtf((float)((2 * NB + 1) * (2 * NB + 1) - 8 * L))) * 0.5f);
    #pragma unroll
    for (int f = 0; f < 2; ++f) {
        int s0 = bi * NB - bi * (bi - 1) / 2;
        int s1 = (bi + 1) * NB - (bi + 1) * bi / 2;
        if (L >= s1) ++bi;
        else if (L < s0) --bi;
    }
    int sbi = bi * NB - bi * (bi - 1) / 2;
    int bj = bi + (L - sbi);
    bool diag = (bi == bj);

    const int t = threadIdx.x;
    const int l = t & 63;
    const int w = t >> 6;

    if (t < TB) {
        float4 ci = c4[bi * TB + t];
        rc4[t] = ci;
        rsq[t] = ci.x * ci.x + ci.y * ci.y + ci.z * ci.z;
    }
    __syncthreads();

    float4 cj = c4[bj * TB + l];
    float sqj = cj.x * cj.x + cj.y * cj.y + cj.z * cj.z;

    float colacc = 0.f;
    #pragma unroll
    for (int rr = 0; rr < 16; ++rr) {
        int r = w * 16 + rr;
        float k = kraw_f(rc4[r], rsq[r], cj, sqj);
        if (diag && r == l) k = 0.f;
        colacc += k;
        rowbuf[r][l] = k;
    }
    __syncthreads();

    // row sums: thread t -> row r = t>>2, quarter q = t&3 (adjacent lanes)
    {
        int r = t >> 2, q = t & 3;
        float p = 0.f;
        #pragma unroll
        for (int m = 0; m < 16; ++m) p += rowbuf[r][q * 16 + m];
        p += __shfl_xor(p, 1, 64);
        p += __shfl_xor(p, 2, 64);
        if (q == 0) atomicAdd(&rsum[bi * TB + r], p);
    }
    if (!diag) atomicAdd(&rsum[bj * TB + l], colacc);
}

// --- kernel 3: fused K write + MFMA GEMM (round-19 EXACT, 117.1 µs proven) -
__global__ __launch_bounds__(256, 2) void main_k(
    const float4* __restrict__ c4, const float* __restrict__ rsum,
    const __bf16* __restrict__ latT, float* __restrict__ outp, float* __restrict__ Kout) {

    __shared__ __bf16 Alds[BM][LDB];    // 4.6 KB, normalized K tile
    __shared__ __bf16 Blin[kD * BK];    // 16 KB, swizzled physical layout
    __shared__ float4 c4row[BM];
    __shared__ float  sqrow[BM];
    __shared__ float  invrow[BM];

    const int t = threadIdx.x;
    const int i0 = blockIdx.x * BM;
    const int jstrip = blockIdx.y * (kN / JSPLIT);

    if (t < BM) {
        float4 ci = c4[i0 + t];
        c4row[t] = ci;
        sqrow[t] = ci.x * ci.x + ci.y * ci.y + ci.z * ci.z;
        invrow[t] = 1.0f / (rsum[i0 + t] + 1e-8f);
    }
    __syncthreads();

    const int lane = t & 63;
    const int wave = t >> 6;

    // K-tile compute mapping: col pair {2*c2, 2*c2+1}, rows rb..rb+3
    const int c2 = t & 31;
    const int rb = (t >> 5) * 4;

    // hoist this thread's 4 fixed rows into registers (r11-proven)
    float4 rc[4]; float rs[4], rv[4];
    #pragma unroll
    for (int rr = 0; rr < 4; ++rr) {
        rc[rr] = c4row[rb + rr];
        rs[rr] = sqrow[rb + rr];
        rv[rr] = invrow[rb + rr];
    }

    // MFMA fragment addressing (r9/r10-proven)
    const int arow = lane & 15;
    const int koff = (lane >> 4) * 8;          // elements
    const int dbase = wave * 32;
    const int bswz = ((dbase + arow) & 7) << 4; // source/read XOR (involution)

    // staging: dest byte = it*4096 + t*16 -> (row = it*32 + t/8, col-byte =
    // (t&7)*16); source col-byte pre-swizzled by ^((row&7)<<4)
    const int srow = t >> 3;
    const int scolb = ((t & 7) ^ (srow & 7)) << 4;

    v4f acc[2][2];
    #pragma unroll
    for (int rt = 0; rt < 2; ++rt)
        #pragma unroll
        for (int dt = 0; dt < 2; ++dt) acc[rt][dt] = (v4f){0.f, 0.f, 0.f, 0.f};

    for (int cb = 0; cb < kN / JSPLIT / BK; ++cb) {
        const int j0 = jstrip + cb * BK;

        // issue async B staging first (flies under the kraw compute)
        #pragma unroll
        for (int it = 0; it < 4; ++it) {
            int row = it * 32 + srow;
            const char* src = (const char*)latT + ((size_t)row * kN + j0) * 2 + scolb;
            char* dst = (char*)Blin + it * 4096 + t * 16;
            gload16(src, dst);
        }

        // K tile (32 x 64): cols {gjA, gjB}, rows rb..rb+3; kraw once per elem
        const int gjA = j0 + 2 * c2, gjB = gjA + 1;
        const float4 cjA = c4[gjA];
        const float4 cjB = c4[gjB];
        const float sqA = cjA.x * cjA.x + cjA.y * cjA.y + cjA.z * cjA.z;
        const float sqB = cjB.x * cjB.x + cjB.y * cjB.y + cjB.z * cjB.z;
        #pragma unroll
        for (int rr = 0; rr < 4; ++rr) {
            int r = rb + rr, gi = i0 + r;
            float kA = (gi == gjA) ? 0.0f : kraw_f(rc[rr], rs[rr], cjA, sqA);
            float kB = (gi == gjB) ? 0.0f : kraw_f(rc[rr], rs[rr], cjB, sqB);
            float knA = kA * rv[rr];
            float knB = kB * rv[rr];
            float2 st = {knA, knB};
            *reinterpret_cast<float2*>(Kout + (size_t)gi * kN + gjA) = st;  // 256B/row coalesced
            __bf16 hA = (__bf16)knA, hB = (__bf16)knB;
            unsigned pk = ((unsigned)*(unsigned short*)&hB << 16) | *(unsigned short*)&hA;
            *reinterpret_cast<unsigned*>(&Alds[r][2 * c2]) = pk;
        }
        __syncthreads();

        // MFMA: A row-tiles {0,1} x B dim-tiles {0,1}
        #pragma unroll
        for (int kk = 0; kk < 2; ++kk) {
            v8bf a0 = *reinterpret_cast<const v8bf*>(&Alds[arow][kk * 32 + koff]);
            v8bf a1 = *reinterpret_cast<const v8bf*>(&Alds[16 + arow][kk * 32 + koff]);
            const int bc = kk * 64 + koff * 2;    // logical byte col
            const char* bp0 = (const char*)Blin + (dbase + arow) * 128 + (bc ^ bswz);
            const char* bp1 = (const char*)Blin + (dbase + 16 + arow) * 128 + (bc ^ bswz);
            v8bf b0 = *reinterpret_cast<const v8bf*>(bp0);
            v8bf b1 = *reinterpret_cast<const v8bf*>(bp1);
            acc[0][0] = __builtin_amdgcn_mfma_f32_16x16x32_bf16(a0, b0, acc[0][0], 0, 0, 0);
            acc[0][1] = __builtin_amdgcn_mfma_f32_16x16x32_bf16(a0, b1, acc[0][1], 0, 0, 0);
            acc[1][0] = __builtin_amdgcn_mfma_f32_16x16x32_bf16(a1, b0, acc[1][0], 0, 0, 0);
            acc[1][1] = __builtin_amdgcn_mfma_f32_16x16x32_bf16(a1, b1, acc[1][1], 0, 0, 0);
        }
        __syncthreads();
    }

    // epilogue: D frag col = lane&15 (dim), row = (lane>>4)*4 + q  [m89 proven]
    const int row = (lane >> 4) * 4;
    const int col0 = wave * 32 + (lane & 15);
    #pragma unroll
    for (int rt = 0; rt < 2; ++rt)
        #pragma unroll
        for (int dt = 0; dt < 2; ++dt)
            #pragma unroll
            for (int q = 0; q < 4; ++q)
                atomicAdd(&outp[(size_t)(i0 + rt * 16 + row + q) * kD + col0 + dt * 16],
                          acc[rt][dt][q]);
}

extern "C" void kernel_launch(void* const* d_in, const int* in_sizes, int n_in,
                              void* d_out, int out_size, void* d_ws, size_t ws_size,
                              hipStream_t stream) {
    const float* latent = (const float*)d_in[0];
    const float* coords = (const float*)d_in[1];
    const float* alpha  = (const float*)d_in[2];

    float* outp = (float*)d_out;                    // [8192][128]
    float* Kout = (float*)d_out + (size_t)kN * kD;  // [8192][8192]

    // ws layout: byte-identical to the proven footprint.
    char* ws = (char*)d_ws;
    __bf16* latT = (__bf16*)ws;                                   // 2 MiB
    float4* c4   = (float4*)(ws + 2u * 1024 * 1024);              // 128 KiB
    float*  rsum = (float*)(ws + 2u * 1024 * 1024 + 128 * 1024);  // 32 KiB

    transpose_k<<<dim3(kN / 32, kD / 32), dim3(256), 0, stream>>>(
        latent, coords, alpha, latT, outp, c4, rsum);
    rowsum_sym_k<<<dim3(NB * (NB + 1) / 2), dim3(256), 0, stream>>>(c4, rsum);
    main_k<<<dim3(kN / BM, JSPLIT), dim3(256), 0, stream>>>(c4, rsum, latT, outp, Kout);
}

// Round 23
// 108.031 us; speedup vs baseline: 1.8771x; 1.0451x over previous
//
#include <hip/hip_runtime.h>
#include <hip/hip_bf16.h>

constexpr int kN = 8192;
constexpr int kD = 128;
constexpr int BM = 32;      // rows per block in main kernel (2 MFMA row-tiles)
constexpr int BK = 64;      // j-chunk
constexpr int JSPLIT = 8;   // j-range strips (grid at 2048 blocks)
constexpr int LDB = 72;     // A-tile LDS row stride: 144B, 16B-aligned (r19-proven)
constexpr int TB = 64;      // rowsum tile
constexpr int NB = kN / TB; // 128

typedef __bf16 v8bf __attribute__((ext_vector_type(8)));
typedef float  v4f  __attribute__((ext_vector_type(4)));
typedef float  v2f  __attribute__((ext_vector_type(2)));

// async global->LDS, 16B per lane (r10-proven).
__device__ __forceinline__ void gload16(const void* g, void* l) {
    __builtin_amdgcn_global_load_lds(
        (const __attribute__((address_space(1))) void*)g,
        (__attribute__((address_space(3))) void*)l, 16, 0, 0);
}

// K_raw with 3 transcendentals (round-8 proven), scalar form (aux kernels).
__device__ __forceinline__ float kraw_f(float4 ci, float sqi, float4 cj, float sqj) {
    float d2 = sqi + sqj - 2.0f * (ci.x * cj.x + ci.y * cj.y + ci.z * cj.z);
    d2 = fmaxf(d2, 1e-12f);
    float Dd = __builtin_amdgcn_sqrtf(d2);
    float a = 0.5f * (ci.w + cj.w);
    float t = a * (-0.5f * __builtin_amdgcn_logf(d2));                // -a*log2(D)
    t = fminf(fmaxf(t, -26.575424759098897f), 9.965784284662087f);   // log2(1e-8), log2(1000)
    float K = __builtin_amdgcn_exp2f(fmaf(Dd, -0.12022458674074695f, t));
    return fminf(K, 1000.0f);  // K >= 0 always
}

// --- kernel 1: transpose latent -> latT bf16; zero outp; fused pack (r22) --
__global__ void transpose_k(const float* __restrict__ latent,
                            const float* __restrict__ coords,
                            const float* __restrict__ alpha,
                            __bf16* __restrict__ latT, float* __restrict__ outp,
                            float4* __restrict__ c4, float* __restrict__ rsum) {
    __shared__ float tile[32][33];
    int t = threadIdx.x;
    int tx = t & 31, ty = t >> 5;          // 32 x 8
    int j0 = blockIdx.x * 32, d0 = blockIdx.y * 32;

    if (blockIdx.y == 0 && t < 32) {
        int j = blockIdx.x * 32 + t;       // 256 x 32 = 8192 points
        c4[j] = make_float4(coords[3 * j], coords[3 * j + 1], coords[3 * j + 2], alpha[j]);
        rsum[j] = 0.0f;                    // consumed by rowsum_sym_k
    }

    #pragma unroll
    for (int i = 0; i < 32; i += 8)
        tile[ty + i][tx] = latent[(size_t)(j0 + ty + i) * kD + d0 + tx];

    // zero outp: grid (256,4) x 256 threads x 4 floats = kN*kD, bijective.
    {
        size_t base = (((size_t)blockIdx.x * 4 + blockIdx.y) * 256 + t) * 4;
        v4f z = {0.f, 0.f, 0.f, 0.f};
        *reinterpret_cast<v4f*>(outp + base) = z;   // consumed by main_k later
    }
    __syncthreads();
    #pragma unroll
    for (int i = 0; i < 32; i += 8)
        latT[(size_t)(d0 + ty + i) * kN + j0 + tx] = (__bf16)tile[tx][ty + i];
}

// --- kernel 2: SYMMETRIC row sums (round-11 proven) ------------------------
__global__ __launch_bounds__(256) void rowsum_sym_k(const float4* __restrict__ c4,
                                                    float* __restrict__ rsum) {
    __shared__ float4 rc4[TB];
    __shared__ float  rsq[TB];
    __shared__ float  rowbuf[TB][TB + 1];   // 16.25 KB

    // decode triangular pair (bi <= bj) from linear block index
    int L = blockIdx.x;
    int bi = (int)((2 * NB + 1 - sqrtf((float)((2 * NB + 1) * (2 * NB + 1) - 8 * L))) * 0.5f);
    #pragma unroll
    for (int f = 0; f < 2; ++f) {
        int s0 = bi * NB - bi * (bi - 1) / 2;
        int s1 = (bi + 1) * NB - (bi + 1) * bi / 2;
        if (L >= s1) ++bi;
        else if (L < s0) --bi;
    }
    int sbi = bi * NB - bi * (bi - 1) / 2;
    int bj = bi + (L - sbi);
    bool diag = (bi == bj);

    const int t = threadIdx.x;
    const int l = t & 63;
    const int w = t >> 6;

    if (t < TB) {
        float4 ci = c4[bi * TB + t];
        rc4[t] = ci;
        rsq[t] = ci.x * ci.x + ci.y * ci.y + ci.z * ci.z;
    }
    __syncthreads();

    float4 cj = c4[bj * TB + l];
    float sqj = cj.x * cj.x + cj.y * cj.y + cj.z * cj.z;

    float colacc = 0.f;
    #pragma unroll
    for (int rr = 0; rr < 16; ++rr) {
        int r = w * 16 + rr;
        float k = kraw_f(rc4[r], rsq[r], cj, sqj);
        if (diag && r == l) k = 0.f;
        colacc += k;
        rowbuf[r][l] = k;
    }
    __syncthreads();

    // row sums: thread t -> row r = t>>2, quarter q = t&3 (adjacent lanes)
    {
        int r = t >> 2, q = t & 3;
        float p = 0.f;
        #pragma unroll
        for (int m = 0; m < 16; ++m) p += rowbuf[r][q * 16 + m];
        p += __shfl_xor(p, 1, 64);
        p += __shfl_xor(p, 2, 64);
        if (q == 0) atomicAdd(&rsum[bi * TB + r], p);
    }
    if (!diag) atomicAdd(&rsum[bj * TB + l], colacc);
}

// --- kernel 3: fused K write + MFMA GEMM (r22 structure, PACKED-FP32 kraw) -
// The (kA,kB) column-pair math is written on float2 ext_vectors so the
// compiler emits full-rate v_pk_{fma,add,mul,max,min}_f32 — halves the
// non-transcendental VALU count of the dominant phase. Transcendentals
// (sqrt/log/exp2) remain scalar x2. Same per-element operation order.
__global__ __launch_bounds__(256, 2) void main_k(
    const float4* __restrict__ c4, const float* __restrict__ rsum,
    const __bf16* __restrict__ latT, float* __restrict__ outp, float* __restrict__ Kout) {

    __shared__ __bf16 Alds[BM][LDB];    // 4.6 KB, normalized K tile
    __shared__ __bf16 Blin[kD * BK];    // 16 KB, swizzled physical layout
    __shared__ float4 c4row[BM];
    __shared__ float  sqrow[BM];
    __shared__ float  invrow[BM];

    const int t = threadIdx.x;
    const int i0 = blockIdx.x * BM;
    const int jstrip = blockIdx.y * (kN / JSPLIT);

    if (t < BM) {
        float4 ci = c4[i0 + t];
        c4row[t] = ci;
        sqrow[t] = ci.x * ci.x + ci.y * ci.y + ci.z * ci.z;
        invrow[t] = 1.0f / (rsum[i0 + t] + 1e-8f);
    }
    __syncthreads();

    const int lane = t & 63;
    const int wave = t >> 6;

    // K-tile compute mapping: col pair {2*c2, 2*c2+1}, rows rb..rb+3
    const int c2 = t & 31;
    const int rb = (t >> 5) * 4;

    // hoist this thread's 4 fixed rows into registers (r11-proven);
    // rc[].w pre-halved for the packed a = hwi + hwj form.
    float4 rc[4]; float rs[4], rv[4];
    #pragma unroll
    for (int rr = 0; rr < 4; ++rr) {
        rc[rr] = c4row[rb + rr];
        rc[rr].w *= 0.5f;
        rs[rr] = sqrow[rb + rr];
        rv[rr] = invrow[rb + rr];
    }

    // MFMA fragment addressing (r9/r10-proven)
    const int arow = lane & 15;
    const int koff = (lane >> 4) * 8;          // elements
    const int dbase = wave * 32;
    const int bswz = ((dbase + arow) & 7) << 4; // source/read XOR (involution)

    // staging: dest byte = it*4096 + t*16 -> (row = it*32 + t/8, col-byte =
    // (t&7)*16); source col-byte pre-swizzled by ^((row&7)<<4)
    const int srow = t >> 3;
    const int scolb = ((t & 7) ^ (srow & 7)) << 4;

    v4f acc[2][2];
    #pragma unroll
    for (int rt = 0; rt < 2; ++rt)
        #pragma unroll
        for (int dt = 0; dt < 2; ++dt) acc[rt][dt] = (v4f){0.f, 0.f, 0.f, 0.f};

    for (int cb = 0; cb < kN / JSPLIT / BK; ++cb) {
        const int j0 = jstrip + cb * BK;

        // issue async B staging first (flies under the kraw compute)
        #pragma unroll
        for (int it = 0; it < 4; ++it) {
            int row = it * 32 + srow;
            const char* src = (const char*)latT + ((size_t)row * kN + j0) * 2 + scolb;
            char* dst = (char*)Blin + it * 4096 + t * 16;
            gload16(src, dst);
        }

        // K tile (32 x 64): packed column-pair {gjA, gjB}, rows rb..rb+3
        const int gjA = j0 + 2 * c2, gjB = gjA + 1;
        const float4 cjA = c4[gjA];
        const float4 cjB = c4[gjB];
        const v2f cx  = {cjA.x, cjB.x};
        const v2f cy  = {cjA.y, cjB.y};
        const v2f cz  = {cjA.z, cjB.z};
        const v2f hwj = {0.5f * cjA.w, 0.5f * cjB.w};
        const v2f csq = {cjA.x * cjA.x + cjA.y * cjA.y + cjA.z * cjA.z,
                         cjB.x * cjB.x + cjB.y * cjB.y + cjB.z * cjB.z};
        #pragma unroll
        for (int rr = 0; rr < 4; ++rr) {
            int r = rb + rr, gi = i0 + r;
            // packed kraw pair (v_pk_* VALU; scalar trans x2)
            v2f d2 = (rs[rr] + csq) - 2.0f * (cx * rc[rr].x + cy * rc[rr].y + cz * rc[rr].z);
            d2 = __builtin_elementwise_max(d2, (v2f)1e-12f);
            v2f Dd = {__builtin_amdgcn_sqrtf(d2.x), __builtin_amdgcn_sqrtf(d2.y)};
            v2f lg = {__builtin_amdgcn_logf(d2.x), __builtin_amdgcn_logf(d2.y)};
            v2f a = rc[rr].w + hwj;                       // 0.5*(wi+wj)
            v2f tt = a * (-0.5f * lg);                    // -a*log2(D)
            tt = __builtin_elementwise_min(
                     __builtin_elementwise_max(tt, (v2f)(-26.575424759098897f)),
                     (v2f)9.965784284662087f);
            v2f earg = Dd * (-0.12022458674074695f) + tt;
            v2f K = {__builtin_amdgcn_exp2f(earg.x), __builtin_amdgcn_exp2f(earg.y)};
            K = __builtin_elementwise_min(K, (v2f)1000.0f);
            float knA = (gi == gjA) ? 0.0f : K.x * rv[rr];
            float knB = (gi == gjB) ? 0.0f : K.y * rv[rr];
            float2 st = {knA, knB};
            *reinterpret_cast<float2*>(Kout + (size_t)gi * kN + gjA) = st;  // 256B/row coalesced
            __bf16 hA = (__bf16)knA, hB = (__bf16)knB;
            unsigned pk = ((unsigned)*(unsigned short*)&hB << 16) | *(unsigned short*)&hA;
            *reinterpret_cast<unsigned*>(&Alds[r][2 * c2]) = pk;
        }
        __syncthreads();

        // MFMA: A row-tiles {0,1} x B dim-tiles {0,1}
        #pragma unroll
        for (int kk = 0; kk < 2; ++kk) {
            v8bf a0 = *reinterpret_cast<const v8bf*>(&Alds[arow][kk * 32 + koff]);
            v8bf a1 = *reinterpret_cast<const v8bf*>(&Alds[16 + arow][kk * 32 + koff]);
            const int bc = kk * 64 + koff * 2;    // logical byte col
            const char* bp0 = (const char*)Blin + (dbase + arow) * 128 + (bc ^ bswz);
            const char* bp1 = (const char*)Blin + (dbase + 16 + arow) * 128 + (bc ^ bswz);
            v8bf b0 = *reinterpret_cast<const v8bf*>(bp0);
            v8bf b1 = *reinterpret_cast<const v8bf*>(bp1);
            acc[0][0] = __builtin_amdgcn_mfma_f32_16x16x32_bf16(a0, b0, acc[0][0], 0, 0, 0);
            acc[0][1] = __builtin_amdgcn_mfma_f32_16x16x32_bf16(a0, b1, acc[0][1], 0, 0, 0);
            acc[1][0] = __builtin_amdgcn_mfma_f32_16x16x32_bf16(a1, b0, acc[1][0], 0, 0, 0);
            acc[1][1] = __builtin_amdgcn_mfma_f32_16x16x32_bf16(a1, b1, acc[1][1], 0, 0, 0);
        }
        __syncthreads();
    }

    // epilogue: D frag col = lane&15 (dim), row = (lane>>4)*4 + q  [m89 proven]
    const int row = (lane >> 4) * 4;
    const int col0 = wave * 32 + (lane & 15);
    #pragma unroll
    for (int rt = 0; rt < 2; ++rt)
        #pragma unroll
        for (int dt = 0; dt < 2; ++dt)
            #pragma unroll
            for (int q = 0; q < 4; ++q)
                atomicAdd(&outp[(size_t)(i0 + rt * 16 + row + q) * kD + col0 + dt * 16],
                          acc[rt][dt][q]);
}

extern "C" void kernel_launch(void* const* d_in, const int* in_sizes, int n_in,
                              void* d_out, int out_size, void* d_ws, size_t ws_size,
                              hipStream_t stream) {
    const float* latent = (const float*)d_in[0];
    const float* coords = (const float*)d_in[1];
    const float* alpha  = (const float*)d_in[2];

    float* outp = (float*)d_out;                    // [8192][128]
    float* Kout = (float*)d_out + (size_t)kN * kD;  // [8192][8192]

    // ws layout: byte-identical to the proven footprint.
    char* ws = (char*)d_ws;
    __bf16* latT = (__bf16*)ws;                                   // 2 MiB
    float4* c4   = (float4*)(ws + 2u * 1024 * 1024);              // 128 KiB
    float*  rsum = (float*)(ws + 2u * 1024 * 1024 + 128 * 1024);  // 32 KiB

    transpose_k<<<dim3(kN / 32, kD / 32), dim3(256), 0, stream>>>(
        latent, coords, alpha, latT, outp, c4, rsum);
    rowsum_sym_k<<<dim3(NB * (NB + 1) / 2), dim3(256), 0, stream>>>(c4, rsum);
    main_k<<<dim3(kN / BM, JSPLIT), dim3(256), 0, stream>>>(c4, rsum, latT, outp, Kout);
}